// Round 4
// baseline (1846.191 us; speedup 1.0000x reference)
//
#include <hip/hip_runtime.h>

#define G    256
#define CCH  16
#define HIDN 128
#define TS   16
#define LDSW 19   // padded LDS row stride (18 used), breaks bank aliasing
#define CSTRIDE (18 * LDSW)
#define XS_FLOATS  (CCH * CSTRIDE)    // 5472 floats (21.9 KB)
#define W2T_FLOATS (HIDN * CCH)       // 2048 floats ( 8.2 KB)
#define B1_FLOATS  (HIDN)             //  128 floats ( 0.5 KB)
// total LDS 30.6 KB -> 5 blocks/CU; VGPR ~100 -> 4-5 waves/SIMD

// ---------------- Kernel 1: conv + MLP + residual + pre_life ----------------
// Weight-stream pipe assignment (the point of this revision):
//   w1  -> per-lane global_load_dwordx4 (vmcnt pipe, deep pipelining, vL1-resident
//          24KB < 32KB). Forced vector via opaque VGPR zero offset: the scalar
//          path (s_load) has no pipelining and thrashes the 16KB K$.
//   w2t -> LDS broadcast, 4 ds_read_b128 per k (transposed at staging).
//   b1  -> LDS broadcast, 1 ds_read_b32 per k.
// lgkmcnt now carries ONLY LDS; vmcnt only w1 -> counted waits, no full drains.
__global__ __launch_bounds__(256) void nca_compute(
    const float* __restrict__ x, const float* __restrict__ w1,
    const float* __restrict__ b1, const float* __restrict__ w2,
    const float* __restrict__ um, float* __restrict__ out,
    float* __restrict__ alpha_new)
{
    __shared__ __align__(16) float lds[XS_FLOATS + W2T_FLOATS + B1_FLOATS];
    float* __restrict__ w2ts = lds + XS_FLOATS;        // [k][c], 64B rows
    float* __restrict__ b1s  = w2ts + W2T_FLOATS;

    const int tx = threadIdx.x, ty = threadIdx.y;
    const int bx = blockIdx.x * TS, by = blockIdx.y * TS, b = blockIdx.z;
    const int tid = ty * TS + tx;

    // ---- stage 18x18 halo tile of all 16 channels (zero-pad OOB) ----
    const float* xb = x + (size_t)b * CCH * G * G;
    for (int i = tid; i < CCH * 18 * 18; i += 256) {
        int c   = i / (18 * 18);
        int rem = i % (18 * 18);
        int r   = rem / 18;
        int col = rem % 18;
        int gy = by + r - 1, gx = bx + col - 1;
        float v = 0.f;
        if (gy >= 0 && gy < G && gx >= 0 && gx < G)
            v = xb[(size_t)c * G * G + (size_t)gy * G + gx];
        lds[c * CSTRIDE + r * LDSW + col] = v;
    }
    // ---- stage w2^T and b1 (tiny, L2-resident re-reads) ----
    for (int i = tid; i < W2T_FLOATS; i += 256) {
        int c = i >> 7, k = i & 127;          // w2 is [C][HIDN]
        w2ts[k * CCH + c] = w2[i];
    }
    if (tid < HIDN) b1s[tid] = b1[tid];
    __syncthreads();

    // ---- perception y[48]: per channel [identity, sobel_x/8, sobel_y/8] ----
    float y[48];
    #pragma unroll
    for (int c = 0; c < CCH; c++) {
        const float* xc = &lds[c * CSTRIDE + ty * LDSW + tx];
        float a00 = xc[0],        a01 = xc[1],            a02 = xc[2];
        float a10 = xc[LDSW],     a11 = xc[LDSW + 1],     a12 = xc[LDSW + 2];
        float a20 = xc[2 * LDSW], a21 = xc[2 * LDSW + 1], a22 = xc[2 * LDSW + 2];
        y[3 * c]     = a11;
        y[3 * c + 1] = ((a02 - a00) + 2.f * (a12 - a10) + (a22 - a20)) * 0.125f;
        y[3 * c + 2] = ((a20 - a00) + 2.f * (a21 - a01) + (a22 - a02)) * 0.125f;
    }

    // ---- pre_life: 3x3 maxpool of alpha (ch 3); zero-pad ok since 0.1 > 0 ----
    float mp = -1e30f;
    {
        const float* xa = &lds[3 * CSTRIDE + ty * LDSW + tx];
        #pragma unroll
        for (int dy = 0; dy < 3; dy++)
            #pragma unroll
            for (int dx = 0; dx < 3; dx++)
                mp = fmaxf(mp, xa[dy * LDSW + dx]);
    }
    const bool pre = mp > 0.1f;
    const int gy = by + ty, gx = bx + tx;
    const float m = um[(size_t)b * G * G + (size_t)gy * G + gx];

    // ---- opaque VGPR zero: forces w1 loads onto the vector (vmcnt) pipe ----
    int vzero;
    asm volatile("v_mov_b32 %0, 0" : "=v"(vzero));
    const float* __restrict__ w1d = w1 + vzero;

    float acc[CCH];
    #pragma unroll
    for (int c = 0; c < CCH; c++) acc[c] = 0.f;

    // ---- MLP: 64 FMA/k vs 12 pipelined vL1 dwordx4 + 5 LDS broadcasts ----
    #pragma unroll 2
    for (int k = 0; k < HIDN; k++) {
        const float4* w1r = (const float4*)(w1d + k * 48);  // 192B-aligned
        const float bk = b1s[k];
        float h0 = bk, h1 = 0.f, h2 = 0.f, h3 = 0.f;        // 4-way dep break
        #pragma unroll
        for (int q = 0; q < 12; q++) {
            float4 w = w1r[q];
            h0 = fmaf(w.x, y[4 * q    ], h0);
            h1 = fmaf(w.y, y[4 * q + 1], h1);
            h2 = fmaf(w.z, y[4 * q + 2], h2);
            h3 = fmaf(w.w, y[4 * q + 3], h3);
        }
        const float hk = fmaxf((h0 + h1) + (h2 + h3), 0.f);
        const float4* w2r = (const float4*)(w2ts + k * CCH); // 64B-aligned row
        #pragma unroll
        for (int q = 0; q < 4; q++) {
            float4 w = w2r[q];
            acc[4 * q    ] = fmaf(w.x, hk, acc[4 * q    ]);
            acc[4 * q + 1] = fmaf(w.y, hk, acc[4 * q + 1]);
            acc[4 * q + 2] = fmaf(w.z, hk, acc[4 * q + 2]);
            acc[4 * q + 3] = fmaf(w.w, hk, acc[4 * q + 3]);
        }
    }

    // ---- epilogue: residual (center = y[3c]), pre_life, pristine alpha ----
    const size_t pix   = (size_t)gy * G + gx;
    const size_t obase = (size_t)b * CCH * G * G + pix;
    #pragma unroll
    for (int c = 0; c < CCH; c++) {
        float xn = y[3 * c] + acc[c] * m;
        if (c == 3) alpha_new[(size_t)b * G * G + pix] = xn;  // pre-mask copy
        out[obase + (size_t)c * G * G] = pre ? xn : 0.f;
    }
}

// ---------------- Kernel 2: post_life mask ----------------
// 32x32 tile per block (2048 blocks, was 8192 launch-overhead-bound).
// Separable 3x3 maxpool via LDS row-max. Re-zeroing pre-dead pixels is
// idempotent (life = pre & post), so only alpha_new is read.
__global__ __launch_bounds__(256) void nca_mask(
    const float* __restrict__ alpha_new, float* __restrict__ out)
{
    __shared__ float na[34 * 36];   // halo alpha, padded stride
    __shared__ float rm[34 * 33];   // horizontal 3-max
    const int tx = threadIdx.x, ty = threadIdx.y;
    const int bx = blockIdx.x * 32, by = blockIdx.y * 32, b = blockIdx.z;
    const int tid = ty * 16 + tx;

    const float* nb = alpha_new + (size_t)b * G * G;
    for (int i = tid; i < 34 * 34; i += 256) {
        int r = i / 34, c = i % 34;
        int gy = by + r - 1, gx = bx + c - 1;
        float v = -1e30f;
        if (gy >= 0 && gy < G && gx >= 0 && gx < G)
            v = nb[(size_t)gy * G + gx];
        na[r * 36 + c] = v;
    }
    __syncthreads();

    for (int i = tid; i < 34 * 32; i += 256) {
        int r = i / 32, c = i % 32;
        const float* p = &na[r * 36 + c];
        rm[r * 33 + c] = fmaxf(fmaxf(p[0], p[1]), p[2]);
    }
    __syncthreads();

    #pragma unroll
    for (int jr = 0; jr < 2; jr++) {
        #pragma unroll
        for (int jc = 0; jc < 2; jc++) {
            const int pr = ty + 16 * jr, pc = tx + 16 * jc;
            float pooled = fmaxf(fmaxf(rm[pr * 33 + pc], rm[(pr + 1) * 33 + pc]),
                                 rm[(pr + 2) * 33 + pc]);
            if (!(pooled > 0.1f)) {
                const size_t obase = (size_t)b * CCH * G * G
                                   + (size_t)(by + pr) * G + (bx + pc);
                #pragma unroll
                for (int c = 0; c < CCH; c++)
                    out[obase + (size_t)c * G * G] = 0.f;
            }
        }
    }
}

extern "C" void kernel_launch(void* const* d_in, const int* in_sizes, int n_in,
                              void* d_out, int out_size, void* d_ws, size_t ws_size,
                              hipStream_t stream) {
    const float* x  = (const float*)d_in[0];
    const float* w1 = (const float*)d_in[1];
    const float* b1 = (const float*)d_in[2];
    const float* w2 = (const float*)d_in[3];
    const float* um = (const float*)d_in[4];
    float* out = (float*)d_out;
    float* alpha_new = (float*)d_ws;   // B*G*G floats = 8.4 MB scratch

    dim3 gridC(G / TS, G / TS, 32);
    dim3 blockC(TS, TS);
    nca_compute<<<gridC, blockC, 0, stream>>>(x, w1, b1, w2, um, out, alpha_new);

    dim3 gridM(G / 32, G / 32, 32);
    dim3 blockM(16, 16);
    nca_mask<<<gridM, blockM, 0, stream>>>(alpha_new, out);
}

// Round 5
// 796.340 us; speedup vs baseline: 2.3183x; 2.3183x over previous
//
#include <hip/hip_runtime.h>

#define G    256
#define CCH  16
#define HIDN 128
#define TS   16
#define LDSW 19   // padded LDS row stride (18 used), breaks bank aliasing
#define CSTRIDE (18 * LDSW)
#define XS_FLOATS (CCH * CSTRIDE)     // 5472 floats (21.9 KB)

// ---------------- Kernel 0: transpose w2 [C][HIDN] -> w2t [HIDN][C] ----------------
// 8 KB once per launch; makes the per-k scalar weight stream contiguous:
// w2t row k = ONE 64B cache line (vs 16 strided lines using 4B each -- the
// baseline's 46%-duty stall was this 1KB/k K$ miss train).
__global__ void w2_transpose(const float* __restrict__ w2, float* __restrict__ w2t)
{
    const int i = threadIdx.x;            // 256 threads, 8 iters
    for (int j = i; j < CCH * HIDN; j += 256) {
        int c = j >> 7, k = j & 127;      // w2 is [C][HIDN]
        w2t[k * CCH + c] = w2[j];
    }
}

// ---------------- Kernel 1: conv + MLP + residual + pre_life ----------------
// All weights stay on the scalar (K$) pipe -- proven best home (R2: LDS pipe
// oversubscribed 6x; R4: VMEM pipe needs per-lane addressing, 2.5x worse).
// Per k: 4 contiguous lines (3x s_load_dwordx16 for w1 row, 1x for w2t row),
// software-pipelined 2-deep by unroll-2.
__global__ __launch_bounds__(256) void nca_compute(
    const float* __restrict__ x, const float* __restrict__ w1,
    const float* __restrict__ b1, const float* __restrict__ w2t,
    const float* __restrict__ um, float* __restrict__ out,
    float* __restrict__ alpha_new)
{
    __shared__ __align__(16) float lds[XS_FLOATS];
    const int tx = threadIdx.x, ty = threadIdx.y;
    const int bx = blockIdx.x * TS, by = blockIdx.y * TS, b = blockIdx.z;
    const int tid = ty * TS + tx;

    // ---- stage 18x18 halo tile of all 16 channels (zero-pad OOB) ----
    const float* xb = x + (size_t)b * CCH * G * G;
    for (int i = tid; i < CCH * 18 * 18; i += 256) {
        int c   = i / (18 * 18);
        int rem = i % (18 * 18);
        int r   = rem / 18;
        int col = rem % 18;
        int gy = by + r - 1, gx = bx + col - 1;
        float v = 0.f;
        if (gy >= 0 && gy < G && gx >= 0 && gx < G)
            v = xb[(size_t)c * G * G + (size_t)gy * G + gx];
        lds[c * CSTRIDE + r * LDSW + col] = v;
    }
    __syncthreads();

    // ---- perception y[48]: per channel [identity, sobel_x/8, sobel_y/8] ----
    float y[48];
    #pragma unroll
    for (int c = 0; c < CCH; c++) {
        const float* xc = &lds[c * CSTRIDE + ty * LDSW + tx];
        float a00 = xc[0],        a01 = xc[1],            a02 = xc[2];
        float a10 = xc[LDSW],     a11 = xc[LDSW + 1],     a12 = xc[LDSW + 2];
        float a20 = xc[2 * LDSW], a21 = xc[2 * LDSW + 1], a22 = xc[2 * LDSW + 2];
        y[3 * c]     = a11;
        y[3 * c + 1] = ((a02 - a00) + 2.f * (a12 - a10) + (a22 - a20)) * 0.125f;
        y[3 * c + 2] = ((a20 - a00) + 2.f * (a21 - a01) + (a22 - a02)) * 0.125f;
    }

    // ---- pre_life: 3x3 maxpool of alpha (ch 3); zero-pad ok since 0.1 > 0 ----
    float mp = -1e30f;
    {
        const float* xa = &lds[3 * CSTRIDE + ty * LDSW + tx];
        #pragma unroll
        for (int dy = 0; dy < 3; dy++)
            #pragma unroll
            for (int dx = 0; dx < 3; dx++)
                mp = fmaxf(mp, xa[dy * LDSW + dx]);
    }
    const bool pre = mp > 0.1f;
    const int gy = by + ty, gx = bx + tx;
    const float m = um[(size_t)b * G * G + (size_t)gy * G + gx];

    float acc[CCH];
    #pragma unroll
    for (int c = 0; c < CCH; c++) acc[c] = 0.f;

    // ---- MLP: per k, 64 FMA vs 4 contiguous scalar lines (pipelined) ----
    #pragma unroll 2
    for (int k = 0; k < HIDN; k++) {
        const float4* w1r = (const float4*)(w1 + k * 48);    // 3 lines, uniform
        const float4* w2r = (const float4*)(w2t + k * CCH);  // 1 line, uniform
        float h0 = b1[k], h1 = 0.f, h2 = 0.f, h3 = 0.f;      // 4-way dep break
        #pragma unroll
        for (int q = 0; q < 12; q++) {
            float4 w = w1r[q];
            h0 = fmaf(w.x, y[4 * q    ], h0);
            h1 = fmaf(w.y, y[4 * q + 1], h1);
            h2 = fmaf(w.z, y[4 * q + 2], h2);
            h3 = fmaf(w.w, y[4 * q + 3], h3);
        }
        const float hk = fmaxf((h0 + h1) + (h2 + h3), 0.f);
        #pragma unroll
        for (int q = 0; q < 4; q++) {
            float4 w = w2r[q];
            acc[4 * q    ] = fmaf(w.x, hk, acc[4 * q    ]);
            acc[4 * q + 1] = fmaf(w.y, hk, acc[4 * q + 1]);
            acc[4 * q + 2] = fmaf(w.z, hk, acc[4 * q + 2]);
            acc[4 * q + 3] = fmaf(w.w, hk, acc[4 * q + 3]);
        }
    }

    // ---- epilogue: residual (center = y[3c]), pre_life, pristine alpha ----
    const size_t pix   = (size_t)gy * G + gx;
    const size_t obase = (size_t)b * CCH * G * G + pix;
    #pragma unroll
    for (int c = 0; c < CCH; c++) {
        float xn = y[3 * c] + acc[c] * m;
        if (c == 3) alpha_new[(size_t)b * G * G + pix] = xn;  // pre-mask copy
        out[obase + (size_t)c * G * G] = pre ? xn : 0.f;
    }
}

// ---------------- Kernel 2: post_life mask ----------------
// 32x32 tile per block (2048 blocks). Separable 3x3 maxpool via LDS row-max.
// Re-zeroing pre-dead pixels is idempotent (life = pre & post) -> only
// alpha_new is read.
__global__ __launch_bounds__(256) void nca_mask(
    const float* __restrict__ alpha_new, float* __restrict__ out)
{
    __shared__ float na[34 * 36];   // halo alpha, padded stride
    __shared__ float rm[34 * 33];   // horizontal 3-max
    const int tx = threadIdx.x, ty = threadIdx.y;
    const int bx = blockIdx.x * 32, by = blockIdx.y * 32, b = blockIdx.z;
    const int tid = ty * 16 + tx;

    const float* nb = alpha_new + (size_t)b * G * G;
    for (int i = tid; i < 34 * 34; i += 256) {
        int r = i / 34, c = i % 34;
        int gy = by + r - 1, gx = bx + c - 1;
        float v = -1e30f;
        if (gy >= 0 && gy < G && gx >= 0 && gx < G)
            v = nb[(size_t)gy * G + gx];
        na[r * 36 + c] = v;
    }
    __syncthreads();

    for (int i = tid; i < 34 * 32; i += 256) {
        int r = i / 32, c = i % 32;
        const float* p = &na[r * 36 + c];
        rm[r * 33 + c] = fmaxf(fmaxf(p[0], p[1]), p[2]);
    }
    __syncthreads();

    #pragma unroll
    for (int jr = 0; jr < 2; jr++) {
        #pragma unroll
        for (int jc = 0; jc < 2; jc++) {
            const int pr = ty + 16 * jr, pc = tx + 16 * jc;
            float pooled = fmaxf(fmaxf(rm[pr * 33 + pc], rm[(pr + 1) * 33 + pc]),
                                 rm[(pr + 2) * 33 + pc]);
            if (!(pooled > 0.1f)) {
                const size_t obase = (size_t)b * CCH * G * G
                                   + (size_t)(by + pr) * G + (bx + pc);
                #pragma unroll
                for (int c = 0; c < CCH; c++)
                    out[obase + (size_t)c * G * G] = 0.f;
            }
        }
    }
}

extern "C" void kernel_launch(void* const* d_in, const int* in_sizes, int n_in,
                              void* d_out, int out_size, void* d_ws, size_t ws_size,
                              hipStream_t stream) {
    const float* x  = (const float*)d_in[0];
    const float* w1 = (const float*)d_in[1];
    const float* b1 = (const float*)d_in[2];
    const float* w2 = (const float*)d_in[3];
    const float* um = (const float*)d_in[4];
    float* out = (float*)d_out;

    float* w2t       = (float*)d_ws;               // 2048 floats (8 KB)
    float* alpha_new = (float*)d_ws + 2048;        // B*G*G floats (8.4 MB)

    w2_transpose<<<dim3(1), dim3(256), 0, stream>>>(w2, w2t);

    dim3 gridC(G / TS, G / TS, 32);
    dim3 blockC(TS, TS);
    nca_compute<<<gridC, blockC, 0, stream>>>(x, w1, b1, w2t, um, out, alpha_new);

    dim3 gridM(G / 32, G / 32, 32);
    dim3 blockM(16, 16);
    nca_mask<<<gridM, blockM, 0, stream>>>(alpha_new, out);
}